// Round 3
// baseline (267.862 us; speedup 1.0000x reference)
//
#include <hip/hip_runtime.h>

#define NB 8
#define CC 32
#define HH 256
#define WW 512
#define DD 64
#define PAD 64
#define RPITCH (WW + PAD)   // 576 words per padded r row in LDS
#define CHUNK 8             // channels per LDS pass
#define NCHUNK (CC / CHUNK) // 4

typedef const __attribute__((address_space(1))) void gv_t;
typedef __attribute__((address_space(3))) void lv_t;

__device__ __forceinline__ void gload_lds16(const float* g, float* lds) {
    __builtin_amdgcn_global_load_lds((gv_t*)g, (lv_t*)lds, 16, 0, 0);
}

__global__ __launch_bounds__(512) void cost_volume_kernel(
    const float* __restrict__ L, const float* __restrict__ R, float* __restrict__ O)
{
    // double-buffered: 2 x (16 KiB l + 18 KiB r) = 68 KiB -> 2 blocks/CU (VGPR-capped anyway)
    __shared__ float lA[2][CHUNK * WW];
    __shared__ float rB[2][CHUNK * RPITCH];

    const int tid = threadIdx.x;
    const int row = blockIdx.x;          // n*H + h
    const int n = row >> 8;
    const int h = row & 255;
    const size_t inbase = (size_t)n * (CC * HH * WW) + (size_t)h * WW;

    // zero the 64-float left pad of each r row in BOTH buffers, once.
    // staging never touches words [0,PAD) of a row, so pads stay zero.
    if (tid < 2 * CHUNK * 16) {
        const int b = tid >> 7, c = (tid >> 4) & 7, q = tid & 15;
        *reinterpret_cast<float4*>(&rB[b][c * RPITCH + q * 4]) =
            make_float4(0.f, 0.f, 0.f, 0.f);
    }

    // thread -> (d-tile, w-chunk)
    const int wave = tid >> 6, lane = tid & 63;
    const int d0 = (wave & 3) * 16;
    const int cw = ((wave >> 2) << 6) + lane;   // [0,128)
    const int w0 = cw * 4;
    const int rbase = PAD + w0 - d0 - 16;       // in [0, 556]

    float acc[16][4];
    #pragma unroll
    for (int dd = 0; dd < 16; ++dd)
        #pragma unroll
        for (int j = 0; j < 4; ++j) acc[dd][j] = 0.f;

    // async stage of one 8-channel chunk into buffer `buf`:
    // per wave, each of the 4 calls is one contiguous 1 KiB segment
    // (wave-uniform base + lane*16) -> global_load_lds width-16 legal.
    auto stage = [&](int buf, int ch) {
        const int c0 = ch * CHUNK;
        #pragma unroll
        for (int it = 0; it < 2; ++it) {
            const int f = tid + it * 512;
            const int c = f >> 7, q = f & 127;
            const size_t g = inbase + (size_t)(c0 + c) * (HH * WW) + (size_t)q * 4;
            gload_lds16(L + g, &lA[buf][c * WW + q * 4]);
            gload_lds16(R + g, &rB[buf][c * RPITCH + PAD + q * 4]);
        }
    };

    stage(0, 0);
    __syncthreads();   // drain prologue stage + pad zeroing

    #pragma unroll
    for (int ch = 0; ch < NCHUNK; ++ch) {
        const int buf = ch & 1;
        if (ch + 1 < NCHUNK) stage(buf ^ 1, ch + 1);   // prefetch flies during compute

        #pragma unroll
        for (int c = 0; c < CHUNK; ++c) {
            const float4 lv = *reinterpret_cast<const float4*>(&lA[buf][c * WW + w0]);
            float rwin[20];
            #pragma unroll
            for (int k = 0; k < 5; ++k) {
                const float4 rv = *reinterpret_cast<const float4*>(&rB[buf][c * RPITCH + rbase + k * 4]);
                rwin[k * 4 + 0] = rv.x; rwin[k * 4 + 1] = rv.y;
                rwin[k * 4 + 2] = rv.z; rwin[k * 4 + 3] = rv.w;
            }
            const float lvv[4] = {lv.x, lv.y, lv.z, lv.w};
            #pragma unroll
            for (int dd = 0; dd < 16; ++dd)
                #pragma unroll
                for (int j = 0; j < 4; ++j)
                    acc[dd][j] = fmaf(lvv[j], rwin[16 + j - dd], acc[dd][j]);
        }

        __syncthreads();   // next-chunk data ready; buf free for overwrite
    }

    const float inv = 1.0f / 32.0f;
    const size_t obase = (size_t)n * ((size_t)DD * HH * WW) + (size_t)h * WW + w0;
    #pragma unroll
    for (int dd = 0; dd < 16; ++dd) {
        float4 o;
        o.x = acc[dd][0] * inv; o.y = acc[dd][1] * inv;
        o.z = acc[dd][2] * inv; o.w = acc[dd][3] * inv;
        *reinterpret_cast<float4*>(&O[obase + (size_t)(d0 + dd) * (HH * WW)]) = o;
    }
}

extern "C" void kernel_launch(void* const* d_in, const int* in_sizes, int n_in,
                              void* d_out, int out_size, void* d_ws, size_t ws_size,
                              hipStream_t stream) {
    const float* L = (const float*)d_in[0];
    const float* R = (const float*)d_in[1];
    float* O = (float*)d_out;
    cost_volume_kernel<<<NB * HH, 512, 0, stream>>>(L, R, O);
}

// Round 5
// 135.260 us; speedup vs baseline: 1.9803x; 1.9803x over previous
//
#include <hip/hip_runtime.h>

#define NB 8
#define CC 32
#define HH 256
#define WW 512
#define DD 64
#define PAD 64
#define RPITCH (WW + PAD)   // 576 words per padded r row in LDS
#define CHUNK 8             // channels per LDS pass
#define NCHUNK (CC / CHUNK) // 4

__global__ __launch_bounds__(512) void cost_volume_kernel(
    const float* __restrict__ L, const float* __restrict__ R, float* __restrict__ O)
{
    // single buffer, exactly R2's structure: 34 KiB
    __shared__ float lA[CHUNK * WW];
    __shared__ float rB[CHUNK * RPITCH];

    const int tid = threadIdx.x;
    const int row = blockIdx.x;          // n*H + h
    const int n = row >> 8;
    const int h = row & 255;
    const size_t inbase = (size_t)n * (CC * HH * WW) + (size_t)h * WW;

    // zero the 64-float left pad of each r row, once; staging never touches
    // words [0,PAD) of a row, so pads stay zero across all chunks.
    if (tid < CHUNK * 16) {
        const int c = tid >> 4, q = tid & 15;
        *reinterpret_cast<float4*>(&rB[c * RPITCH + q * 4]) =
            make_float4(0.f, 0.f, 0.f, 0.f);
    }

    // thread -> (d-tile, w-chunk)
    const int wave = tid >> 6, lane = tid & 63;
    const int d0 = (wave & 3) * 16;
    const int cw = ((wave >> 2) << 6) + lane;   // [0,128)
    const int w0 = cw * 4;
    const int rbase = PAD + w0 - d0 - 16;       // in [0, 556]

    float acc[16][4];
    #pragma unroll
    for (int dd = 0; dd < 16; ++dd)
        #pragma unroll
        for (int j = 0; j < 4; ++j) acc[dd][j] = 0.f;

    // register prefetch: global->reg issued one chunk early (thread-local;
    // LDS/barrier structure is byte-identical to the verified R2 kernel).
    float4 lr0, lr1, rr0, rr1;
    const int f0 = tid, c_0 = f0 >> 7, q_0 = f0 & 127;
    const int f1 = tid + 512, c_1 = f1 >> 7, q_1 = f1 & 127;

    auto ld = [&](int ch) {
        const int c0 = ch * CHUNK;
        const size_t g0 = inbase + (size_t)(c0 + c_0) * (HH * WW);
        const size_t g1 = inbase + (size_t)(c0 + c_1) * (HH * WW);
        lr0 = reinterpret_cast<const float4*>(L + g0)[q_0];
        rr0 = reinterpret_cast<const float4*>(R + g0)[q_0];
        lr1 = reinterpret_cast<const float4*>(L + g1)[q_1];
        rr1 = reinterpret_cast<const float4*>(R + g1)[q_1];
    };

    ld(0);   // chunk-0 loads fly during pad-zeroing/launch

    for (int ch = 0; ch < NCHUNK; ++ch) {
        __syncthreads();   // compute(ch-1) done -> LDS writable (and pad visible at ch=0)

        // reg -> LDS (vmcnt wait lands here, ~1 compute-phase after issue)
        *reinterpret_cast<float4*>(&lA[c_0 * WW + q_0 * 4]) = lr0;
        *reinterpret_cast<float4*>(&rB[c_0 * RPITCH + PAD + q_0 * 4]) = rr0;
        *reinterpret_cast<float4*>(&lA[c_1 * WW + q_1 * 4]) = lr1;
        *reinterpret_cast<float4*>(&rB[c_1 * RPITCH + PAD + q_1 * 4]) = rr1;

        if (ch + 1 < NCHUNK) ld(ch + 1);   // issue next chunk's loads NOW

        __syncthreads();   // stage(ch) visible before compute(ch)

        #pragma unroll
        for (int c = 0; c < CHUNK; ++c) {
            const float4 lv = *reinterpret_cast<const float4*>(&lA[c * WW + w0]);
            float rwin[20];
            #pragma unroll
            for (int k = 0; k < 5; ++k) {
                const float4 rv = *reinterpret_cast<const float4*>(&rB[c * RPITCH + rbase + k * 4]);
                rwin[k * 4 + 0] = rv.x; rwin[k * 4 + 1] = rv.y;
                rwin[k * 4 + 2] = rv.z; rwin[k * 4 + 3] = rv.w;
            }
            const float lvv[4] = {lv.x, lv.y, lv.z, lv.w};
            #pragma unroll
            for (int dd = 0; dd < 16; ++dd)
                #pragma unroll
                for (int j = 0; j < 4; ++j)
                    acc[dd][j] = fmaf(lvv[j], rwin[16 + j - dd], acc[dd][j]);
        }
    }

    const float inv = 1.0f / 32.0f;
    const size_t obase = (size_t)n * ((size_t)DD * HH * WW) + (size_t)h * WW + w0;
    #pragma unroll
    for (int dd = 0; dd < 16; ++dd) {
        float4 o;
        o.x = acc[dd][0] * inv; o.y = acc[dd][1] * inv;
        o.z = acc[dd][2] * inv; o.w = acc[dd][3] * inv;
        *reinterpret_cast<float4*>(&O[obase + (size_t)(d0 + dd) * (HH * WW)]) = o;
    }
}

extern "C" void kernel_launch(void* const* d_in, const int* in_sizes, int n_in,
                              void* d_out, int out_size, void* d_ws, size_t ws_size,
                              hipStream_t stream) {
    const float* L = (const float*)d_in[0];
    const float* R = (const float*)d_in[1];
    float* O = (float*)d_out;
    cost_volume_kernel<<<NB * HH, 512, 0, stream>>>(L, R, O);
}